// Round 3
// baseline (298.074 us; speedup 1.0000x reference)
//
#include <hip/hip_runtime.h>

// Problem constants (fixed by the reference file).
#define IMG_H 4096
#define IMG_W 4096
#define NPIX (IMG_H * IMG_W)

#define TILE 64
#define TILES_X (IMG_W / TILE)          // 64
#define TILES_Y (IMG_H / TILE)          // 64
#define NBINS (TILES_X * TILES_Y)       // 4096
#define BIN_CAP 256                     // lambda=49 boxes/bin; 256 is ~19 sigma
#define CSTRIDE 32                      // one counter per 128B cacheline

#define ZERO_BLOCKS 2048                // fused zero-fill grid
#define F4_TOTAL (3 * NPIX / 4)         // 12,582,912 float4s of output
#define F4_PER_BLOCK (F4_TOTAL / ZERO_BLOCKS)   // 6144
#define F4_PER_THREAD (F4_PER_BLOCK / 256)      // 24

typedef float __attribute__((ext_vector_type(4))) f32x4;

// ---------------------------------------------------------------------------
// Kernel 1 (fused): bin boxes AND zero the 192-MiB output background.
//  Binning is latency/atomic-bound with ~0 BW; zeroing is pure write BW.
//  Fusing overlaps the two (the box load+atomicAdd chain is issued first and
//  completes under the 96-KB nontemporal store stream of each block),
//  removing the serial 192-MiB memset dispatch (~29 us) from R2.
// Packed bin entry:
//   bits  0..17  box index (200k < 2^18)
//   bits 18..23  lx = cx & 63
//   bits 24..29  ly = cy & 63
//   bit  30      valid (full 3x3 stamp fits in image)
// For a fixed pixel only the box-index bits differ, so atomicMax(packed)
// == last-write-wins (highest box index). Counters padded 1/128B line.
// ---------------------------------------------------------------------------
__global__ __launch_bounds__(256) void bin_zero_kernel(
    const float* __restrict__ boxes,
    int* __restrict__ counts,
    int* __restrict__ bins,
    float* __restrict__ out,
    int nboxes)
{
    int tid = threadIdx.x;
    int bid = blockIdx.x;
    int b = bid * 256 + tid;

    // ---- issue the binning chain first (latency hides under the stores) ----
    if (b < nboxes) {
        float4 bx = reinterpret_cast<const float4*>(boxes)[b];
        int cx = (int)(bx.x * (float)IMG_W);
        int cy = (int)(bx.y * (float)IMG_H);
        int valid = (cx >= 1 && cx <= IMG_W - 2 && cy >= 1 && cy <= IMG_H - 2) ? 1 : 0;
        int pack = b | ((cx & 63) << 18) | ((cy & 63) << 24) | (valid << 30);
        int bin = (cy >> 6) * TILES_X + (cx >> 6);
        int slot = atomicAdd(&counts[bin * CSTRIDE], 1);
        if (slot < BIN_CAP) bins[bin * BIN_CAP + slot] = pack;
    }

    // ---- stream-zero this block's 96-KB slice of the output (NT stores) ----
    f32x4 z = { 0.f, 0.f, 0.f, 0.f };
    f32x4* o = reinterpret_cast<f32x4*>(out) + (size_t)bid * F4_PER_BLOCK + tid;
#pragma unroll
    for (int i = 0; i < F4_PER_THREAD; ++i)
        __builtin_nontemporal_store(z, o + i * 256);
}

// ---------------------------------------------------------------------------
// Kernel 2: one block per 64x64 tile. SPARSE epilogue (background zeros come
// from bin_zero_kernel): heat float4 chunk stored iff any of the 9-neighbor
// bits is set (~30% of chunks); sizemap chunks stored iff any of 4 lidx >= 0
// (~1.2%). Each pixel has exactly one owner thread -> exact, no RMW.
// ---------------------------------------------------------------------------
__global__ __launch_bounds__(256) void tile_kernel(
    const float* __restrict__ boxes,
    const float* __restrict__ mount,
    const int* __restrict__ counts,
    const int* __restrict__ bins,
    float* __restrict__ heat,
    float* __restrict__ s0,
    float* __restrict__ s1)
{
    __shared__ __align__(16) int lidx[TILE * TILE];         // 16 KB, packed winner per pixel
    __shared__ __align__(16) unsigned int bm[TILE + 2][4];  // 66 rows x 96 bits (halo bitmap)
    __shared__ int pfx[10];
    __shared__ int bbase[9];

    int tid = threadIdx.x;
    int tile = blockIdx.x;
    int tx = tile & (TILES_X - 1);
    int ty = tile >> 6;

    // Issue the 9 counts loads FIRST so their latency overlaps the LDS init;
    // 16-lane shfl prefix scan (one barrier total in the prologue).
    if (tid < 16) {
        int cnt = 0, base = 0;
        int nty = ty + tid / 3 - 1;
        int ntx = tx + (tid % 3) - 1;
        if (tid < 9 && (unsigned)nty < (unsigned)TILES_Y && (unsigned)ntx < (unsigned)TILES_X) {
            int bin = nty * TILES_X + ntx;
            cnt = min(counts[bin * CSTRIDE], BIN_CAP);
            base = bin * BIN_CAP;
        }
        int inc = cnt;
#pragma unroll
        for (int d = 1; d < 16; d <<= 1) {
            int v = __shfl_up(inc, d, 16);
            if (tid >= d) inc += v;
        }
        if (tid < 10) pfx[tid] = inc - cnt;   // exclusive offsets; pfx[9] = S
        if (tid < 9) bbase[tid] = base;
    }

    int4 neg1 = make_int4(-1, -1, -1, -1);
#pragma unroll
    for (int i = 0; i < 4; ++i)
        reinterpret_cast<int4*>(lidx)[tid + 256 * i] = neg1;
    if (tid < TILE + 2)
        *reinterpret_cast<uint4*>(&bm[tid][0]) = make_uint4(0u, 0u, 0u, 0u);
    __syncthreads();

    int S = pfx[9];
    for (int i = tid; i < S; i += 256) {
        int j = 0;
        while (pfx[j + 1] <= i) ++j;
        int p = bins[bbase[j] + (i - pfx[j])];
        int lx = (p >> 18) & 63;
        int ly = (p >> 24) & 63;
        if (j == 4) atomicMax(&lidx[ly * TILE + lx], p);
        if (p & (1 << 30)) {
            int Lx = lx + (j % 3) * 64 - 64;   // local coords in OUR tile
            int Ly = ly + (j / 3) * 64 - 64;
            if (Lx >= -1 && Lx <= TILE && Ly >= -1 && Ly <= TILE) {
                int pos = Lx + 1;              // 0..65
                atomicOr(&bm[Ly + 1][pos >> 5], 1u << (pos & 31));
            }
        }
    }
    __syncthreads();

    float mvC = mount[4];   // 1.0   (center)
    float mvE = mount[1];   // .6065 (edge)
    float mvK = mount[0];   // .3679 (corner)  -- mvC >= mvE >= mvK
    int ty0 = ty * TILE, tx0 = tx * TILE;

#pragma unroll
    for (int pass = 0; pass < 4; ++pass) {
        int idx = pass * 1024 + tid * 4;   // pixel index in tile
        int r = idx >> 6;                  // row 0..63
        int xb = idx & 63;                 // 0,4,...,60

        uint4 w0 = *(const uint4*)&bm[r][0];
        uint4 w1 = *(const uint4*)&bm[r + 1][0];
        uint4 w2 = *(const uint4*)&bm[r + 2][0];
        unsigned long long V0 = ((unsigned long long)w0.y << 32) | w0.x;
        unsigned long long V1 = ((unsigned long long)w1.y << 32) | w1.x;
        unsigned long long V2 = ((unsigned long long)w2.y << 32) | w2.x;
        if (xb) {
            V0 = (V0 >> xb) | ((unsigned long long)w0.z << (64 - xb));
            V1 = (V1 >> xb) | ((unsigned long long)w1.z << (64 - xb));
            V2 = (V2 >> xb) | ((unsigned long long)w2.z << (64 - xb));
        }
        // bit jj of (V >> (1+dx)) == center present at (row, x=xb+jj+dx)
        unsigned int C = (unsigned int)(V1 >> 1);
        unsigned int E = (unsigned int)V1 | (unsigned int)(V1 >> 2)
                       | (unsigned int)(V0 >> 1) | (unsigned int)(V2 >> 1);
        unsigned int K = (unsigned int)V0 | (unsigned int)(V0 >> 2)
                       | (unsigned int)V2 | (unsigned int)(V2 >> 2);
        unsigned int m = (C | E | K) & 0xFu;

        int g = (ty0 + r) * IMG_W + tx0 + xb;

        if (m) {
            float h[4];
#pragma unroll
            for (int jj = 0; jj < 4; ++jj) {
                float v = 0.f;
                if ((K >> jj) & 1) v = mvK;
                if ((E >> jj) & 1) v = mvE;
                if ((C >> jj) & 1) v = mvC;
                h[jj] = v;
            }
            *reinterpret_cast<float4*>(&heat[g]) = make_float4(h[0], h[1], h[2], h[3]);
        }

        int4 iv = *reinterpret_cast<const int4*>(&lidx[idx]);
        // any component >= 0  <=>  AND of the four has sign bit clear
        if ((iv.x & iv.y & iv.z & iv.w) >= 0) {
            float4 ow = make_float4(0.f, 0.f, 0.f, 0.f);
            float4 oh = make_float4(0.f, 0.f, 0.f, 0.f);
            if (iv.x >= 0) { float4 bb = reinterpret_cast<const float4*>(boxes)[iv.x & 0x3FFFF]; ow.x = bb.z; oh.x = bb.w; }
            if (iv.y >= 0) { float4 bb = reinterpret_cast<const float4*>(boxes)[iv.y & 0x3FFFF]; ow.y = bb.z; oh.y = bb.w; }
            if (iv.z >= 0) { float4 bb = reinterpret_cast<const float4*>(boxes)[iv.z & 0x3FFFF]; ow.z = bb.z; oh.z = bb.w; }
            if (iv.w >= 0) { float4 bb = reinterpret_cast<const float4*>(boxes)[iv.w & 0x3FFFF]; ow.w = bb.z; oh.w = bb.w; }
            *reinterpret_cast<float4*>(&s0[g]) = ow;
            *reinterpret_cast<float4*>(&s1[g]) = oh;
        }
    }
}

extern "C" void kernel_launch(void* const* d_in, const int* in_sizes, int n_in,
                              void* d_out, int out_size, void* d_ws, size_t ws_size,
                              hipStream_t stream) {
    const float* boxes = (const float*)d_in[0];   // [B,4] fp32
    const float* mount = (const float*)d_in[1];   // [3,3] fp32
    int nboxes = in_sizes[0] / 4;

    float* out  = (float*)d_out;
    float* heat = out;               // [1,1,H,W]
    float* s0   = out + NPIX;        // sizemap ch0 (w)
    float* s1   = out + 2 * NPIX;    // sizemap ch1 (h)

    int* counts = (int*)d_ws;                    // 512 KB (padded, 1 counter / 128B line)
    int* bins   = counts + NBINS * CSTRIDE;      // 4 MB

    hipMemsetAsync(counts, 0, NBINS * CSTRIDE * sizeof(int), stream);

    // Fused: zero the 192-MiB output background AND bin the boxes in one
    // BW-saturating dispatch (binning latency hides under the store stream).
    bin_zero_kernel<<<ZERO_BLOCKS, 256, 0, stream>>>(boxes, counts, bins, out, nboxes);

    tile_kernel<<<NBINS, 256, 0, stream>>>(boxes, mount, counts, bins, heat, s0, s1);
}

// Round 4
// 213.973 us; speedup vs baseline: 1.3930x; 1.3930x over previous
//
#include <hip/hip_runtime.h>

// Problem constants (fixed by the reference file).
#define IMG_H 4096
#define IMG_W 4096
#define NPIX (IMG_H * IMG_W)

#define TILE 64
#define TILES_X (IMG_W / TILE)          // 64
#define TILES_Y (IMG_H / TILE)          // 64
#define NBINS (TILES_X * TILES_Y)       // 4096
#define BIN_CAP 256                     // lambda=49 boxes/bin; 256 is ~19 sigma
#define CSTRIDE 32                      // one counter per 128B cacheline

// ---------------------------------------------------------------------------
// Kernel 1: bin boxes by center pixel's 64x64 tile. Entry is PACKED:
//   bits  0..17  box index (200k < 2^18)
//   bits 18..23  lx = cx & 63
//   bits 24..29  ly = cy & 63
//   bit  30      valid (full 3x3 stamp fits in image)
// For a fixed pixel only the box-index bits differ, so atomicMax(packed)
// == last-write-wins (highest box index). Counters padded 1/128B line.
// ---------------------------------------------------------------------------
__global__ __launch_bounds__(256) void bin_boxes_kernel(
    const float* __restrict__ boxes,
    int* __restrict__ counts,
    int* __restrict__ bins,
    int nboxes)
{
    int b = blockIdx.x * blockDim.x + threadIdx.x;
    if (b >= nboxes) return;
    float4 bx = reinterpret_cast<const float4*>(boxes)[b];
    int cx = (int)(bx.x * (float)IMG_W);
    int cy = (int)(bx.y * (float)IMG_H);
    int valid = (cx >= 1 && cx <= IMG_W - 2 && cy >= 1 && cy <= IMG_H - 2) ? 1 : 0;
    int pack = b | ((cx & 63) << 18) | ((cy & 63) << 24) | (valid << 30);
    int bin = (cy >> 6) * TILES_X + (cx >> 6);
    int slot = atomicAdd(&counts[bin * CSTRIDE], 1);
    if (slot < BIN_CAP) bins[bin * BIN_CAP + slot] = pack;
}

// ---------------------------------------------------------------------------
// Kernel 2: one block per 64x64 tile. DENSE epilogue (R1 structure — best
// measured): every pixel chunk written exactly once with regular cached
// float4 stores. Dense stores inside this dispatch overlap with other
// blocks' replay; a separate zero-fill pass measured strictly worse (R2/R3).
// NO nontemporal stores anywhere: 192-MiB NT bursts were measured to drain
// into neighboring dispatches and cut the harness fill from 6.7 to 4.8 TB/s.
// ---------------------------------------------------------------------------
__global__ __launch_bounds__(256) void tile_kernel(
    const float* __restrict__ boxes,
    const float* __restrict__ mount,
    const int* __restrict__ counts,
    const int* __restrict__ bins,
    float* __restrict__ heat,
    float* __restrict__ s0,
    float* __restrict__ s1)
{
    __shared__ __align__(16) int lidx[TILE * TILE];         // 16 KB, packed winner per pixel
    __shared__ __align__(16) unsigned int bm[TILE + 2][4];  // 66 rows x 96 bits (halo bitmap)
    __shared__ int pfx[10];
    __shared__ int bbase[9];

    int tid = threadIdx.x;
    int tile = blockIdx.x;
    int tx = tile & (TILES_X - 1);
    int ty = tile >> 6;

    // Issue the 9 counts loads FIRST so their latency overlaps the LDS init;
    // 16-lane shfl prefix scan (one barrier total in the prologue).
    if (tid < 16) {
        int cnt = 0, base = 0;
        int nty = ty + tid / 3 - 1;
        int ntx = tx + (tid % 3) - 1;
        if (tid < 9 && (unsigned)nty < (unsigned)TILES_Y && (unsigned)ntx < (unsigned)TILES_X) {
            int bin = nty * TILES_X + ntx;
            cnt = min(counts[bin * CSTRIDE], BIN_CAP);
            base = bin * BIN_CAP;
        }
        int inc = cnt;
#pragma unroll
        for (int d = 1; d < 16; d <<= 1) {
            int v = __shfl_up(inc, d, 16);
            if (tid >= d) inc += v;
        }
        if (tid < 10) pfx[tid] = inc - cnt;   // exclusive offsets; pfx[9] = S
        if (tid < 9) bbase[tid] = base;
    }

    int4 neg1 = make_int4(-1, -1, -1, -1);
#pragma unroll
    for (int i = 0; i < 4; ++i)
        reinterpret_cast<int4*>(lidx)[tid + 256 * i] = neg1;
    if (tid < TILE + 2)
        *reinterpret_cast<uint4*>(&bm[tid][0]) = make_uint4(0u, 0u, 0u, 0u);
    __syncthreads();

    int S = pfx[9];
    for (int i = tid; i < S; i += 256) {
        int j = 0;
        while (pfx[j + 1] <= i) ++j;
        int p = bins[bbase[j] + (i - pfx[j])];
        int lx = (p >> 18) & 63;
        int ly = (p >> 24) & 63;
        if (j == 4) atomicMax(&lidx[ly * TILE + lx], p);
        if (p & (1 << 30)) {
            int Lx = lx + (j % 3) * 64 - 64;   // local coords in OUR tile
            int Ly = ly + (j / 3) * 64 - 64;
            if (Lx >= -1 && Lx <= TILE && Ly >= -1 && Ly <= TILE) {
                int pos = Lx + 1;              // 0..65
                atomicOr(&bm[Ly + 1][pos >> 5], 1u << (pos & 31));
            }
        }
    }
    __syncthreads();

    float mvC = mount[4];   // 1.0   (center)
    float mvE = mount[1];   // .6065 (edge)
    float mvK = mount[0];   // .3679 (corner)  -- mvC >= mvE >= mvK
    int ty0 = ty * TILE, tx0 = tx * TILE;

#pragma unroll
    for (int pass = 0; pass < 4; ++pass) {
        int idx = pass * 1024 + tid * 4;   // pixel index in tile
        int r = idx >> 6;                  // row 0..63
        int xb = idx & 63;                 // 0,4,...,60

        uint4 w0 = *(const uint4*)&bm[r][0];
        uint4 w1 = *(const uint4*)&bm[r + 1][0];
        uint4 w2 = *(const uint4*)&bm[r + 2][0];
        unsigned long long V0 = ((unsigned long long)w0.y << 32) | w0.x;
        unsigned long long V1 = ((unsigned long long)w1.y << 32) | w1.x;
        unsigned long long V2 = ((unsigned long long)w2.y << 32) | w2.x;
        if (xb) {
            V0 = (V0 >> xb) | ((unsigned long long)w0.z << (64 - xb));
            V1 = (V1 >> xb) | ((unsigned long long)w1.z << (64 - xb));
            V2 = (V2 >> xb) | ((unsigned long long)w2.z << (64 - xb));
        }
        // bit jj of (V >> (1+dx)) == center present at (row, x=xb+jj+dx)
        unsigned int C = (unsigned int)(V1 >> 1);
        unsigned int E = (unsigned int)V1 | (unsigned int)(V1 >> 2)
                       | (unsigned int)(V0 >> 1) | (unsigned int)(V2 >> 1);
        unsigned int K = (unsigned int)V0 | (unsigned int)(V0 >> 2)
                       | (unsigned int)V2 | (unsigned int)(V2 >> 2);

        float h[4];
#pragma unroll
        for (int jj = 0; jj < 4; ++jj) {
            float v = 0.f;
            if ((K >> jj) & 1) v = mvK;
            if ((E >> jj) & 1) v = mvE;
            if ((C >> jj) & 1) v = mvC;
            h[jj] = v;
        }

        int g = (ty0 + r) * IMG_W + tx0 + xb;
        *reinterpret_cast<float4*>(&heat[g]) = make_float4(h[0], h[1], h[2], h[3]);

        int4 iv = *reinterpret_cast<const int4*>(&lidx[idx]);
        float4 ow = make_float4(0.f, 0.f, 0.f, 0.f);
        float4 oh = make_float4(0.f, 0.f, 0.f, 0.f);
        if (iv.x >= 0) { float4 bb = reinterpret_cast<const float4*>(boxes)[iv.x & 0x3FFFF]; ow.x = bb.z; oh.x = bb.w; }
        if (iv.y >= 0) { float4 bb = reinterpret_cast<const float4*>(boxes)[iv.y & 0x3FFFF]; ow.y = bb.z; oh.y = bb.w; }
        if (iv.z >= 0) { float4 bb = reinterpret_cast<const float4*>(boxes)[iv.z & 0x3FFFF]; ow.z = bb.z; oh.z = bb.w; }
        if (iv.w >= 0) { float4 bb = reinterpret_cast<const float4*>(boxes)[iv.w & 0x3FFFF]; ow.w = bb.z; oh.w = bb.w; }
        *reinterpret_cast<float4*>(&s0[g]) = ow;
        *reinterpret_cast<float4*>(&s1[g]) = oh;
    }
}

extern "C" void kernel_launch(void* const* d_in, const int* in_sizes, int n_in,
                              void* d_out, int out_size, void* d_ws, size_t ws_size,
                              hipStream_t stream) {
    const float* boxes = (const float*)d_in[0];   // [B,4] fp32
    const float* mount = (const float*)d_in[1];   // [3,3] fp32
    int nboxes = in_sizes[0] / 4;

    float* out  = (float*)d_out;
    float* heat = out;               // [1,1,H,W]
    float* s0   = out + NPIX;        // sizemap ch0 (w)
    float* s1   = out + 2 * NPIX;    // sizemap ch1 (h)

    int* counts = (int*)d_ws;                    // 512 KB (padded, 1 counter / 128B line)
    int* bins   = counts + NBINS * CSTRIDE;      // 4 MB

    hipMemsetAsync(counts, 0, NBINS * CSTRIDE * sizeof(int), stream);

    int bgrid = (nboxes + 255) / 256;
    bin_boxes_kernel<<<bgrid, 256, 0, stream>>>(boxes, counts, bins, nboxes);

    tile_kernel<<<NBINS, 256, 0, stream>>>(boxes, mount, counts, bins, heat, s0, s1);
}